// Round 10
// baseline (60.722 us; speedup 1.0000x reference)
//
#include <hip/hip_runtime.h>
#include <cfloat>

// ---------------------------------------------------------------------------
// VQ-VAE vector quantizer forward (MI355X / gfx950)
//   x        [32][64][64][64] f32   (B, D, H, W)
//   codebook [1024][64] f32
// out: x_q transposed back to [B,D,H,W] (8388608 f32)  +  loss scalar (1 f32)
//
// argmin_k ||x - c_k||^2  ==  argmax_k (x . c_k - ||c_k||^2/2)
// Sum_p SSE_p = Sum x^2 - 2 * Sum_p (best_score_p - 1),
//   score = dot + 1 - ||c||^2/2 (C-init), packed-u32 argmax (R5/R9-proven).
//
// R10 = R9 skeleton with 2 ROWS PER BLOCK (grid 1024) to double arithmetic
// intensity per B-load and halve L2 B-traffic:
//   wave = (code-half cw, pos-half pw): 512 codes x 32 positions x 2 rows,
//   32-tile loop, 8 MFMA + 32 merge per tile (covers depth-1 L2 latency).
// mh4 C-init now depth-1-prefetched from global (L2-resident 16 KB) instead
// of LDS -> LDS ~18.6 KB. NO launch_bounds occupancy hint (spill lesson,
// R2/R6/R7/R8). Canary: FETCH~35MB / WRITE~33MB means no spill.
// ---------------------------------------------------------------------------

#define DD    64
#define HHWW  4096         // H*W
#define KC    1024
#define NBLKM 1024         // one block per 2 rows
#define NPOSD 8388608.0f   // N * D

typedef __bf16  bf16x8 __attribute__((ext_vector_type(8)));
typedef float   f32x4  __attribute__((ext_vector_type(4)));

__device__ __forceinline__ unsigned short bf16_bits(float f) {
  unsigned u = __float_as_uint(f);
  return (unsigned short)((u + 0x7FFFu + ((u >> 16) & 1u)) >> 16);  // RNE
}

__device__ __forceinline__ unsigned int umax2(unsigned int a, unsigned int b) {
  return a > b ? a : b;
}

// --- precompute: fragment-ordered bf16 codebook + replicated (1-||c||^2/2) --
__global__ __launch_bounds__(256) void vq_pre(
    const float* __restrict__ cb,          // [1024][64]
    unsigned short* __restrict__ cb_frag,  // [tile=64][kk=2][lane=64][e=8]
    float* __restrict__ hneg4)             // [1024][4] : 1-||c||^2/2, x4
{
  int k = blockIdx.x * 256 + threadIdx.x;
  if (k >= KC) return;
  float c[DD];
  float sum = 0.f;
#pragma unroll
  for (int d = 0; d < DD; ++d) { c[d] = cb[k * DD + d]; sum += c[d] * c[d]; }
  const float m = 1.0f - 0.5f * sum;
  hneg4[k * 4 + 0] = m; hneg4[k * 4 + 1] = m;
  hneg4[k * 4 + 2] = m; hneg4[k * 4 + 3] = m;
  int t = k >> 4, l15 = k & 15;
#pragma unroll
  for (int kk = 0; kk < 2; ++kk)
#pragma unroll
    for (int g = 0; g < 4; ++g)
#pragma unroll
      for (int e = 0; e < 8; ++e)
        cb_frag[(((t * 2 + kk) * 64) + (g * 16 + l15)) * 8 + e] =
            bf16_bits(c[kk * 32 + g * 8 + e]);
}

// --- main: fused distance-GEMM + argmin + loss partial + output write ------
__global__ __launch_bounds__(256) void vq_main(
    const float* __restrict__ x,
    const unsigned short* __restrict__ cb_frag,
    const float* __restrict__ hneg4,
    const float* __restrict__ cb,
    float* __restrict__ out,
    float* __restrict__ partials)
{
  __shared__ unsigned short xfrag[2][4096];  // 16 KB: A-frags, 2 rows
  __shared__ unsigned int   cand[2][2][64];  //  2 KB: (code-half, row, pos)
  __shared__ int            idx_lds[2][64];
  __shared__ float          xred[4];
  __shared__ float          vtred[2];

  const int tid  = threadIdx.x;
  const int wv   = tid >> 6;
  const int lane = tid & 63;
  const int l15  = lane & 15;
  const int g    = lane >> 4;
  const int cw   = wv & 1;     // code half: 512 codes
  const int pw   = wv >> 1;    // pos half: pos-tiles {pw*2, pw*2+1}

  const int row0 = blockIdx.x * 2;       // rows row0, row0+1 (same b)
  const int b    = row0 >> 6;
  const int h0   = row0 & 63;
  const float* xb = x + (size_t)b * DD * HHWW + h0 * 64;  // xb[d*4096 + w]

  // ---- cooperative coalesced x-stage (both rows) -> bf16 frag layout ----
  // float4 #m covers (d = m>>4, w = (m&15)*4 .. +3); 256B segments.
  float xacc = 0.f;
#pragma unroll
  for (int r = 0; r < 2; ++r) {
#pragma unroll
    for (int r4 = 0; r4 < 4; ++r4) {
      const int m  = tid + r4 * 256;
      const int d  = m >> 4;
      const int w4 = m & 15;
      const float4 v4 = *(const float4*)(xb + (size_t)d * HHWW + r * 64 + w4 * 4);
      const int kk = d >> 5, gg = (d >> 3) & 3, e = d & 7;
      const int pt = w4 >> 2;
      const int base = pt * 1024 + kk * 512 + gg * 128 + e;  // + l15*8
      const int lb = (w4 & 3) * 4;
      xacc += v4.x * v4.x + v4.y * v4.y + v4.z * v4.z + v4.w * v4.w;
      xfrag[r][base + (lb + 0) * 8] = bf16_bits(v4.x);
      xfrag[r][base + (lb + 1) * 8] = bf16_bits(v4.y);
      xfrag[r][base + (lb + 2) * 8] = bf16_bits(v4.z);
      xfrag[r][base + (lb + 3) * 8] = bf16_bits(v4.w);
    }
  }

  __syncthreads();                       // xfrag ready

  // ---- A fragments: 2 rows x 2 pos-tiles (pw half) x 2 kk ----
  // layout matches B: row i = lane&15, k = kk*32 + (lane>>4)*8 + e.
  bf16x8 afrag[2][2][2];
#pragma unroll
  for (int r = 0; r < 2; ++r)
#pragma unroll
    for (int j = 0; j < 2; ++j) {
      const int pt = pw * 2 + j;
      afrag[r][j][0] = *(const bf16x8*)(&xfrag[r][pt * 1024 + lane * 8]);
      afrag[r][j][1] = *(const bf16x8*)(&xfrag[r][pt * 1024 + 512 + lane * 8]);
    }

  // ---- this wave's 32 code tiles (codes cw*512 .. +511), depth-1 pf ----
  // best = (score_bits & ~1023) | (1023-code); score ~[0.95,1.05] > 0 so
  // bit pattern is order-preserving; ties prefer LOWER code (argmin).
  unsigned int best[2][2][4];
#pragma unroll
  for (int r = 0; r < 2; ++r)
#pragma unroll
    for (int j = 0; j < 2; ++j)
#pragma unroll
      for (int rr = 0; rr < 4; ++rr) best[r][j][rr] = 0u;

  const unsigned int MASK = 0xFFFFFC00u;
  const int codec0 = 1023 - cw * 512 - l15;
  // cb_frag tile stride = 2048 B; wave chunk = 32 tiles.
  const char*  bb  = (const char*)cb_frag + (size_t)cw * 32 * 2048 + (size_t)lane * 16;
  const f32x4* mhp = (const f32x4*)hneg4 + cw * 512 + l15;   // + t*16 per tile

  bf16x8 nb0 = *(const bf16x8*)(bb);          // depth-1 prefetch (kk=0)
  bf16x8 nb1 = *(const bf16x8*)(bb + 1024);   // kk=1
  f32x4  nmh = mhp[0];

#pragma unroll 4
  for (int t = 0; t < 32; ++t) {
    const bf16x8 b0 = nb0, b1 = nb1;
    const f32x4  mh = nmh;
    const int tn = (t + 1) & 31;
    nb0 = *(const bf16x8*)(bb + tn * 2048);
    nb1 = *(const bf16x8*)(bb + tn * 2048 + 1024);
    nmh = mhp[tn * 16];

    const unsigned int codec = (unsigned int)(codec0 - t * 16);

#pragma unroll
    for (int r = 0; r < 2; ++r)
#pragma unroll
      for (int j = 0; j < 2; ++j) {
        f32x4 acc = __builtin_amdgcn_mfma_f32_16x16x32_bf16(afrag[r][j][0], b0, mh, 0, 0, 0);
        acc = __builtin_amdgcn_mfma_f32_16x16x32_bf16(afrag[r][j][1], b1, acc, 0, 0, 0);
#pragma unroll
        for (int rr = 0; rr < 4; ++rr) {  // C/D: col=l15(code), row=g*4+rr
          const unsigned int p = (__float_as_uint(acc[rr]) & MASK) | codec;
          best[r][j][rr] = umax2(best[r][j][rr], p);
        }
      }
  }

  // ---- cross-lane max over the 16 code columns (l15) ----
#pragma unroll
  for (int r = 0; r < 2; ++r)
#pragma unroll
    for (int j = 0; j < 2; ++j)
#pragma unroll
      for (int rr = 0; rr < 4; ++rr) {
        unsigned int v = best[r][j][rr];
#pragma unroll
        for (int m = 1; m < 16; m <<= 1) {
          unsigned int vo = __shfl_xor(v, m, 64);
          v = umax2(v, vo);
        }
        if (l15 == 0) cand[cw][r][(pw * 2 + j) * 16 + g * 4 + rr] = v;
      }

  // per-wave Sum x^2 reduce
#pragma unroll
  for (int m = 1; m < 64; m <<= 1) xacc += __shfl_xor(xacc, m, 64);
  if (lane == 0) xred[wv] = xacc;

  __syncthreads();                       // cand + xred ready

  // ---- waves 0-1: merge the 2 code-half candidates; loss term ----
  if (tid < 128) {
    const int r = tid >> 6, p = tid & 63;
    const unsigned int v = umax2(cand[0][r][p], cand[1][r][p]);
    idx_lds[r][p] = 1023 - (int)(v & 1023u);
    float vt1 = __uint_as_float(v & MASK) - 1.0f;   // dot - csq/2 (trunc)
#pragma unroll
    for (int m = 1; m < 64; m <<= 1) vt1 += __shfl_xor(vt1, m, 64);
    if ((tid & 63) == 0) vtred[r] = vt1;
  }

  __syncthreads();                       // idx_lds + vtred ready

  if (tid == 0)
    partials[blockIdx.x] =
        (xred[0] + xred[1] + xred[2] + xred[3]) - 2.0f * (vtred[0] + vtred[1]);

  // ---- write quantized output; float4 gather from row-major cb ----
#pragma unroll
  for (int r = 0; r < 2; ++r) {
    const int myidx = idx_lds[r][lane];  // position w = lane
    const float4* crow = (const float4*)(cb + (size_t)myidx * DD) + wv * 4;
    const float4 c0 = crow[0], c1 = crow[1], c2 = crow[2], c3 = crow[3];
    float* ob = out + (size_t)b * DD * HHWW + (h0 + r) * 64 + lane;
    ob[(size_t)(wv * 16 +  0) * HHWW] = c0.x;
    ob[(size_t)(wv * 16 +  1) * HHWW] = c0.y;
    ob[(size_t)(wv * 16 +  2) * HHWW] = c0.z;
    ob[(size_t)(wv * 16 +  3) * HHWW] = c0.w;
    ob[(size_t)(wv * 16 +  4) * HHWW] = c1.x;
    ob[(size_t)(wv * 16 +  5) * HHWW] = c1.y;
    ob[(size_t)(wv * 16 +  6) * HHWW] = c1.z;
    ob[(size_t)(wv * 16 +  7) * HHWW] = c1.w;
    ob[(size_t)(wv * 16 +  8) * HHWW] = c2.x;
    ob[(size_t)(wv * 16 +  9) * HHWW] = c2.y;
    ob[(size_t)(wv * 16 + 10) * HHWW] = c2.z;
    ob[(size_t)(wv * 16 + 11) * HHWW] = c2.w;
    ob[(size_t)(wv * 16 + 12) * HHWW] = c3.x;
    ob[(size_t)(wv * 16 + 13) * HHWW] = c3.y;
    ob[(size_t)(wv * 16 + 14) * HHWW] = c3.z;
    ob[(size_t)(wv * 16 + 15) * HHWW] = c3.w;
  }
}

// --- final loss reduce ------------------------------------------------------
__global__ __launch_bounds__(256) void vq_loss(
    const float* __restrict__ partials, float* __restrict__ loss_out)
{
  __shared__ float sred[4];
  int tid = threadIdx.x;
  float s = 0.f;
  for (int i = tid; i < NBLKM; i += 256) s += partials[i];
#pragma unroll
  for (int m = 1; m < 64; m <<= 1) s += __shfl_xor(s, m, 64);
  if ((tid & 63) == 0) sred[tid >> 6] = s;
  __syncthreads();
  if (tid == 0)
    loss_out[0] = (sred[0] + sred[1] + sred[2] + sred[3]) * (1.25f / NPOSD);
}

extern "C" void kernel_launch(void* const* d_in, const int* in_sizes, int n_in,
                              void* d_out, int out_size, void* d_ws, size_t ws_size,
                              hipStream_t stream) {
  const float* x  = (const float*)d_in[0];
  const float* cb = (const float*)d_in[1];
  float* out      = (float*)d_out;
  float* loss_out = out + 8388608;

  char* ws = (char*)d_ws;
  unsigned short* cb_frag = (unsigned short*)(ws);      // 131072 B
  float* hneg4    = (float*)(ws + 131072);              //  16384 B
  float* partials = (float*)(ws + 147456);              //   8192 B

  vq_pre <<<4,     256, 0, stream>>>(cb, cb_frag, hneg4);
  vq_main<<<NBLKM, 256, 0, stream>>>(x, cb_frag, hneg4, cb, out, partials);
  vq_loss<<<1,     256, 0, stream>>>(partials, loss_out);
}